// Round 3
// baseline (777.256 us; speedup 1.0000x reference)
//
#include <hip/hip_runtime.h>
#include <hip/hip_bf16.h>

#define S 2048
#define D 128
#define NH 16
#define TM 128
#define TN 128

typedef __bf16 bf16x8 __attribute__((ext_vector_type(8)));
typedef float  f32x4  __attribute__((ext_vector_type(4)));
typedef int    i32x4  __attribute__((ext_vector_type(4)));

// Barrier-free design: no LDS, no __syncthreads. Each of the 4 waves in a block
// owns an independent 64x64 output quadrant of the 128x128 tile and loads its
// MFMA fragments directly from global (L1/L2-cached; per-head working set
// Q+K = 2 MB < 4 MB XCD L2). K=128 is too short to amortize a barrier-locked
// LDS staging pipeline -- TLP across independent waves hides latency instead.
__global__ __launch_bounds__(256, 2)   // <=256 VGPR: no spill, 2 waves/SIMD
void alibi_scores(const float* __restrict__ q,
                  const float* __restrict__ k,
                  const float* __restrict__ head_scales,
                  const float* __restrict__ slopes,
                  const float* __restrict__ positions,
                  const int* __restrict__ tok,
                  float* __restrict__ out)
{
    const int tid = threadIdx.x;

    // XCD-aware chunked swizzle (bijective: 8192 % 8 == 0). Each XCD gets a
    // contiguous 1024-block chunk = 4 whole (b,h) heads -> K/Q panels L2-resident.
    const int wgid = blockIdx.x + (blockIdx.y << 4) + (blockIdx.z << 8);
    const int lin  = ((wgid & 7) << 10) | (wgid >> 3);
    const int bh   = lin >> 8;
    const int b    = bh >> 4;          // / NH
    const int h    = bh & 15;          // % NH
    const int tm   = ((lin >> 4) & 15) * TM;
    const int tn   = (lin & 15) * TN;

    const int lane = tid & 63;
    const int wv   = tid >> 6;
    const int wr   = (wv >> 1) * 64;   // wave's Q-row quadrant
    const int wc   = (wv & 1) * 64;    // wave's K-col quadrant
    const int col  = lane & 15;
    const int quad = lane >> 4;

    // Per-lane fragment base pointers. A-frag(16x32): row = col, k = quad*8..+8
    // (8 contiguous floats, 32B-aligned).
    const float* qrow = q + ((size_t)bh * S + (tm + wr + col)) * D + quad * 8;
    const float* krow = k + ((size_t)bh * S + (tn + wc + col)) * D + quad * 8;

    // Hoist ALiBi position gathers so their latency hides under the matmul.
    // Lane needs posQ for its 4 output rows (mi) and posK for its 4x4 cols (ni,r).
    float pq[4];
    f32x4 pk4[4];
    {
        const int* tq = tok + b * S + tm + wr + col;
        const int* tk = tok + b * S + tn + wc + quad * 4;
        #pragma unroll
        for (int mi = 0; mi < 4; ++mi) pq[mi] = positions[tq[mi * 16]];
        #pragma unroll
        for (int ni = 0; ni < 4; ++ni) {
            i32x4 t4 = *reinterpret_cast<const i32x4*>(tk + ni * 16);
            #pragma unroll
            for (int r = 0; r < 4; ++r) pk4[ni][r] = positions[t4[r]];
        }
    }

    f32x4 acc[4][4];
    #pragma unroll
    for (int i = 0; i < 4; ++i)
        #pragma unroll
        for (int j = 0; j < 4; ++j)
            acc[i][j] = (f32x4){0.f, 0.f, 0.f, 0.f};

    // K-loop: 4 steps of 32. Per step: 16 direct global loads (2x dwordx4 per
    // fragment), in-register fp32->bf16 cvt, 16 MFMA. Fully unrolled; compiler
    // schedules loads ahead of use (cap 256 VGPR leaves room for in-flight regs).
    #pragma unroll
    for (int ks = 0; ks < 4; ++ks) {
        bf16x8 qf[4], kf[4];
        #pragma unroll
        for (int mi = 0; mi < 4; ++mi) {
            f32x4 lo = *reinterpret_cast<const f32x4*>(qrow + mi * 16 * D + ks * 32);
            f32x4 hi = *reinterpret_cast<const f32x4*>(qrow + mi * 16 * D + ks * 32 + 4);
            #pragma unroll
            for (int j = 0; j < 4; ++j) {
                qf[mi][j]     = (__bf16)lo[j];
                qf[mi][j + 4] = (__bf16)hi[j];
            }
        }
        #pragma unroll
        for (int ni = 0; ni < 4; ++ni) {
            f32x4 lo = *reinterpret_cast<const f32x4*>(krow + ni * 16 * D + ks * 32);
            f32x4 hi = *reinterpret_cast<const f32x4*>(krow + ni * 16 * D + ks * 32 + 4);
            #pragma unroll
            for (int j = 0; j < 4; ++j) {
                kf[ni][j]     = (__bf16)lo[j];
                kf[ni][j + 4] = (__bf16)hi[j];
            }
        }
        // Swapped operands (harness-verified in R1): A=K-frag, B=Q-frag.
        // C layout: Q-row = lane&15, K-col = (lane>>4)*4 + reg -> lane's 4 acc
        // regs are 4 consecutive output columns (f32x4-storable).
        #pragma unroll
        for (int mi = 0; mi < 4; ++mi)
            #pragma unroll
            for (int ni = 0; ni < 4; ++ni)
                acc[mi][ni] = __builtin_amdgcn_mfma_f32_16x16x32_bf16(
                    kf[ni], qf[mi], acc[mi][ni], 0, 0, 0);
    }

    // Epilogue: scale + ALiBi bias, vectorized f32x4 stores (plain, L2-combined).
    const float scale = head_scales[h] * 0.08838834764831845f; // 1/sqrt(128)
    const float slope = slopes[h];
    float* ob = out + (size_t)bh * S * S;

    #pragma unroll
    for (int mi = 0; mi < 4; ++mi) {
        const float sp = slope * pq[mi];
        float* orow = ob + (size_t)(tm + wr + mi * 16 + col) * S + tn + wc;
        #pragma unroll
        for (int ni = 0; ni < 4; ++ni) {
            f32x4 v;
            #pragma unroll
            for (int r = 0; r < 4; ++r)
                v[r] = acc[mi][ni][r] * scale + (slope * pk4[ni][r] - sp);
            *reinterpret_cast<f32x4*>(orow + ni * 16 + quad * 4) = v;
        }
    }
}

extern "C" void kernel_launch(void* const* d_in, const int* in_sizes, int n_in,
                              void* d_out, int out_size, void* d_ws, size_t ws_size,
                              hipStream_t stream)
{
    (void)in_sizes; (void)n_in; (void)d_ws; (void)ws_size; (void)out_size;
    const float* q  = (const float*)d_in[0];
    const float* k  = (const float*)d_in[1];
    const float* hs = (const float*)d_in[2];
    const float* sl = (const float*)d_in[3];
    const float* ps = (const float*)d_in[4];
    const int*   ti = (const int*)d_in[5];
    float* out      = (float*)d_out;

    dim3 grid(S / TN, S / TM, 2 * NH);  // x=col tile, y=row tile, z=batch*head
    alibi_scores<<<grid, 256, 0, stream>>>(q, k, hs, sl, ps, ti, out);
}